// Round 5
// baseline (820.180 us; speedup 1.0000x reference)
//
#include <hip/hip_runtime.h>
#include <hip/hip_bf16.h>
#include <math.h>

typedef __hip_bfloat16 bf16;
using short8 = __attribute__((ext_vector_type(8))) short;
using f32x4  = __attribute__((ext_vector_type(4))) float;

#define NB 8
#define NC 256
#define NH 128
#define NW 128
#define NHW 16384
#define MID 128

__device__ __forceinline__ float b2f(bf16 v){ return __bfloat162float(v); }
__device__ __forceinline__ bf16 f2b(float v){ return __float2bfloat16(v); }
#define BN_S 0.9999950000374997f  /* 1/sqrt(1+1e-5) */

// ---------------- f32 -> bf16 weight convert ----------------
__global__ __launch_bounds__(256) void k_cvt(const float* __restrict__ src, bf16* __restrict__ dst, int n){
  int i = blockIdx.x*256 + threadIdx.x;
  if(i < n) dst[i] = f2b(src[i]);
}

// ---------------- hm_c3 (m,c,3,3) f32 -> (tau,m,c) bf16 ----------------
__global__ __launch_bounds__(256) void k_trans(const float* __restrict__ src, bf16* __restrict__ dst){
  int i = blockIdx.x*256 + threadIdx.x;
  if(i >= MID*MID*9) return;
  int tau = i % 9; int c = (i/9) % MID; int m = i/(9*MID);
  dst[((size_t)tau*MID + m)*MID + c] = f2b(src[i]);
}

// ============ depthwise 3x3 pad=1: f32 NCHW in -> bf16 channel-blocked out ============
// out layout B8: [b][g=ch/8][pixel][8ch]  (16B per pixel per group)
// grid (16 row-tiles, 32 ch-groups, B); block = 8 rows x 128 cols x 8 ch
__global__ __launch_bounds__(256) void k_dwb(const float* __restrict__ x,
                                             const float* __restrict__ w9,
                                             bf16* __restrict__ outB8){
  __shared__ float tile[8][10][132];
  int tid = threadIdx.x;
  int cg = blockIdx.y, b = blockIdx.z;
  int y0 = blockIdx.x*8;
  // stage 8 ch x 10 rows x 128 f32 (float4-coalesced)
  #pragma unroll
  for(int it=0; it<10; it++){
    int idx = it*256 + tid;
    int c = idx / 320, rem = idx % 320;
    int row = rem >> 5, col4 = rem & 31;
    int gy = y0 - 1 + row;
    float4 v = make_float4(0.f,0.f,0.f,0.f);
    if(gy >= 0 && gy < NH)
      v = *(const float4*)(x + ((size_t)(b*NC + cg*8 + c))*NHW + gy*NW + col4*4);
    *(float4*)&tile[c][row][col4*4] = v;
  }
  __syncthreads();
  int row  = tid >> 5;       // 0..7
  int colb = tid & 31;       // cols colb, +32, +64, +96
  union { ushort u[8]; short8 v; } o[4];
  for(int c=0;c<8;c++){
    float wf[9];
    #pragma unroll
    for(int i=0;i<9;i++) wf[i] = w9[(cg*8+c)*9 + i];
    #pragma unroll
    for(int i=0;i<4;i++){
      int col = colb + 32*i;
      float a = 0.f;
      #pragma unroll
      for(int dr=0;dr<3;dr++){
        #pragma unroll
        for(int dc=0;dc<3;dc++){
          int cc = col + dc - 1;
          float tv = (cc>=0 && cc<NW) ? tile[c][row+dr][cc] : 0.f;
          a += tv * wf[dr*3+dc];
        }
      }
      bf16 ab = f2b(a);
      o[i].u[c] = *(ushort*)&ab;
    }
  }
  #pragma unroll
  for(int i=0;i<4;i++){
    int col = colb + 32*i;
    *(short8*)(outB8 + (((size_t)(b*32+cg))*NHW + (y0+row)*NW + col)*8) = o[i].v;
  }
}

// ============ pointwise GEMM (B8 in, K=256) + bn/relu + epilogue, no LDS/barriers ============
// MODE 0: write all M=128 channels to h1 in B8-16 layout; MODE 1: radius head -> rmapF
template<int MT, int MODE>
__global__ __launch_bounds__(256) void k_pw(const bf16* __restrict__ in8,   // B8: (B,32,NHW,8)
                                            const bf16* __restrict__ wA,    // (M,256) bf16
                                            const float* __restrict__ g,
                                            const float* __restrict__ bias,
                                            const float* __restrict__ hw,
                                            const float* __restrict__ hb,
                                            bf16*  __restrict__ h1B8,       // (B,16,NHW,8)
                                            float* __restrict__ outMap){
  int tid = threadIdx.x;
  int bidx = blockIdx.x;
  int b = bidx >> 8;
  int p0 = (bidx & 255)*64;
  int lane = tid & 63, wave = tid >> 6;
  int n = lane & 15, quad = lane >> 4;
  size_t pix = p0 + wave*16 + n;
  const ushort* inU = (const ushort*)in8;
  const ushort* wU  = (const ushort*)wA;

  f32x4 acc[MT];
  #pragma unroll
  for(int i=0;i<MT;i++){
    #pragma unroll
    for(int r=0;r<4;r++) acc[i][r] = 0.f;
  }
  #pragma unroll
  for(int k0=0;k0<NC;k0+=32){
    short8 bfrag = *(const short8*)&inU[ (((size_t)(b*32) + (k0>>3) + quad)*NHW + pix)*8 ];
    #pragma unroll
    for(int mt=0;mt<MT;mt++){
      short8 afrag = *(const short8*)&wU[(size_t)(mt*16 + n)*NC + k0 + quad*8];
      acc[mt] = __builtin_amdgcn_mfma_f32_16x16x32_bf16(afrag, bfrag, acc[mt], 0, 0, 0);
    }
  }

  if(MODE == 0){
    #pragma unroll
    for(int mt=0;mt<MT;mt++){
      int mg  = mt*2 + (quad>>1);
      int off = (quad&1)*4;
      union { ushort u[4]; ushort4 v; } t;
      #pragma unroll
      for(int r=0;r<4;r++){
        int m = mt*16 + quad*4 + r;
        float v = acc[mt][r]*(g[m]*BN_S) + bias[m];
        bf16 ab = f2b(fmaxf(v, 0.f));
        t.u[r] = *(ushort*)&ab;
      }
      *(ushort4*)((ushort*)h1B8 + (((size_t)(b*16+mg))*NHW + pix)*8 + off) = t.v;
    }
  }else{
    float ph = 0.f;
    #pragma unroll
    for(int mt=0;mt<MT;mt++){
      #pragma unroll
      for(int r=0;r<4;r++){
        int m = mt*16 + quad*4 + r;
        float v = acc[mt][r]*(g[m]*BN_S) + bias[m];
        ph += fmaxf(v, 0.f) * hw[m];
      }
    }
    ph += __shfl_xor(ph, 16);
    ph += __shfl_xor(ph, 32);
    if(lane < 16){
      float sg = 1.f/(1.f + expf(-(ph + hb[0])));
      outMap[(size_t)b*NHW + pix] = 0.03f + sg*0.37f;
    }
  }
}

// ============ 3x3 conv MID->MID (9 masked direct-load GEMMs) + bn/relu + heat head ============
// block = full row (128 px), 4 waves x (2 n-groups x 8 m-tiles); no LDS, no barriers
__global__ __launch_bounds__(256) void k_c3(const bf16* __restrict__ h1B8,  // (B,16,NHW,8)
                                            const bf16* __restrict__ wT,    // (tau,m,c)
                                            const float* __restrict__ g,
                                            const float* __restrict__ bias,
                                            const float* __restrict__ hw,
                                            const float* __restrict__ hb,
                                            float* __restrict__ heatF,
                                            float* __restrict__ out){
  int tid = threadIdx.x;
  int y = blockIdx.x, b = blockIdx.y;
  int lane = tid & 63, wave = tid >> 6;
  int n = lane & 15, quad = lane >> 4;
  const ushort* inU = (const ushort*)h1B8;
  const ushort* wU  = (const ushort*)wT;
  f32x4 acc[8][2];
  #pragma unroll
  for(int i=0;i<8;i++){
    #pragma unroll
    for(int j=0;j<2;j++){
      #pragma unroll
      for(int r=0;r<4;r++) acc[i][j][r] = 0.f;
    }
  }
  for(int dy=0;dy<3;dy++){
    int yy = y + dy - 1;
    if(yy < 0 || yy >= NH) continue;
    for(int dx=0;dx<3;dx++){
      const ushort* wtb = wU + (size_t)(dy*3+dx)*MID*MID;
      int col0 = wave*32 + n + dx - 1;
      int col1 = col0 + 16;
      bool ok0 = (col0>=0) && (col0<NW);
      bool ok1 = (col1>=0) && (col1<NW);
      size_t rowbase = (size_t)yy*NW;
      #pragma unroll
      for(int k0=0;k0<MID;k0+=32){
        size_t gbase = ((size_t)(b*16) + (k0>>3) + quad)*NHW;
        short8 b0 = {0,0,0,0,0,0,0,0};
        short8 b1 = {0,0,0,0,0,0,0,0};
        if(ok0) b0 = *(const short8*)&inU[(gbase + rowbase + col0)*8];
        if(ok1) b1 = *(const short8*)&inU[(gbase + rowbase + col1)*8];
        #pragma unroll
        for(int mt=0;mt<8;mt++){
          short8 a = *(const short8*)&wtb[(size_t)(mt*16 + n)*MID + k0 + quad*8];
          acc[mt][0] = __builtin_amdgcn_mfma_f32_16x16x32_bf16(a, b0, acc[mt][0], 0, 0, 0);
          acc[mt][1] = __builtin_amdgcn_mfma_f32_16x16x32_bf16(a, b1, acc[mt][1], 0, 0, 0);
        }
      }
    }
  }
  #pragma unroll
  for(int ng=0;ng<2;ng++){
    float ph = 0.f;
    #pragma unroll
    for(int mt=0;mt<8;mt++){
      #pragma unroll
      for(int r=0;r<4;r++){
        int m = mt*16 + quad*4 + r;
        float v = acc[mt][ng][r]*(g[m]*BN_S) + bias[m];
        ph += fmaxf(v, 0.f) * hw[m];
      }
    }
    ph += __shfl_xor(ph, 16);
    ph += __shfl_xor(ph, 32);
    if(lane < 16){
      int pix = y*NW + wave*32 + ng*16 + lane;
      float sg = 1.f/(1.f + expf(-(ph + hb[0])));
      heatF[(size_t)b*NHW + pix] = sg;
      out[((size_t)(b*2+1))*NHW + pix] = sg;
    }
  }
}

// ---------------- topk stage 1: per-512px-block top-5 ----------------
__global__ __launch_bounds__(256) void k_topk1(const float* __restrict__ heat,
                                               float* __restrict__ sv_g,   // (B,32,5)
                                               int*   __restrict__ si_g){
  __shared__ float sv[256*5];
  __shared__ int   si[256*5];
  int blk = blockIdx.x, b = blockIdx.y, tid = threadIdx.x;
  const float* hb = heat + (size_t)b*NHW;
  float tv[5]; int ti[5];
  #pragma unroll
  for(int i=0;i<5;i++){ tv[i] = -1.f; ti[i] = 0x7fffffff; }
  for(int s=0;s<2;s++){
    int p = blk*512 + s*256 + tid;
    int y = p >> 7, x = p & 127;
    float v = hb[p];
    float mx = v;
    for(int dy=-1;dy<=1;dy++){
      int yy = y+dy; if(yy<0||yy>=NH) continue;
      for(int dx=-1;dx<=1;dx++){
        int xc = x+dx; if(xc<0||xc>=NW) continue;
        mx = fmaxf(mx, hb[yy*NW+xc]);
      }
    }
    float pv = (v == mx) ? v : 0.f;
    #pragma unroll
    for(int j=0;j<5;j++){
      if(pv > tv[j] || (pv == tv[j] && p < ti[j])){
        for(int q=4;q>j;q--){ tv[q]=tv[q-1]; ti[q]=ti[q-1]; }
        tv[j] = pv; ti[j] = p;
        break;
      }
    }
  }
  #pragma unroll
  for(int i=0;i<5;i++){ sv[tid*5+i] = tv[i]; si[tid*5+i] = ti[i]; }
  __syncthreads();
  if(tid < 64){
    float mv[5]; int mi[5];
    #pragma unroll
    for(int i=0;i<5;i++){ mv[i] = -1.f; mi[i] = 0x7fffffff; }
    for(int s=0;s<4;s++){
      int t2 = tid + s*64;
      for(int i=0;i<5;i++){
        float pv = sv[t2*5+i]; int pi = si[t2*5+i];
        for(int j=0;j<5;j++){
          if(pv > mv[j] || (pv == mv[j] && pi < mi[j])){
            for(int q=4;q>j;q--){ mv[q]=mv[q-1]; mi[q]=mi[q-1]; }
            mv[j] = pv; mi[j] = pi;
            break;
          }
        }
      }
    }
    for(int i=0;i<5;i++){ sv[tid*5+i] = mv[i]; si[tid*5+i] = mi[i]; }
  }
  __syncthreads();
  if(tid == 0){
    float fv[5]; int fi[5];
    #pragma unroll
    for(int i=0;i<5;i++){ fv[i] = -1.f; fi[i] = 0x7fffffff; }
    for(int t2=0;t2<64;t2++){
      for(int i=0;i<5;i++){
        float pv = sv[t2*5+i]; int pi = si[t2*5+i];
        for(int j=0;j<5;j++){
          if(pv > fv[j] || (pv == fv[j] && pi < fi[j])){
            for(int q=4;q>j;q--){ fv[q]=fv[q-1]; fi[q]=fi[q-1]; }
            fv[j] = pv; fi[j] = pi;
            break;
          }
        }
      }
    }
    for(int i=0;i<5;i++){
      sv_g[(b*32 + blk)*5 + i] = fv[i];
      si_g[(b*32 + blk)*5 + i] = fi[i];
    }
  }
}

// ---------------- topk stage 2: rank-select over 160 candidates -> centers ----------------
__global__ __launch_bounds__(256) void k_topk2(const float* __restrict__ sv_g,
                                               const int*   __restrict__ si_g,
                                               float* __restrict__ centers){
  __shared__ float cv[160];
  __shared__ int   ci[160];
  int b = blockIdx.x, tid = threadIdx.x;
  if(tid < 160){ cv[tid] = sv_g[b*160 + tid]; ci[tid] = si_g[b*160 + tid]; }
  __syncthreads();
  if(tid < 160){
    float v = cv[tid]; int idx = ci[tid];
    int rank = 0;
    for(int j=0;j<160;j++){
      float vj = cv[j]; int ij = ci[j];
      rank += (vj > v || (vj == v && ij < idx)) ? 1 : 0;
    }
    if(rank < 5){
      float valid = (v >= 0.1f) ? 1.f : 0.f;
      float row = (float)(idx >> 7);
      float col = (float)(idx & 127);
      float ny = 2.f*row/127.f - 1.f;
      float nx = 2.f*col/127.f - 1.f;
      float* cp = centers + (b*5+rank)*4;
      cp[0] = nx*valid; cp[1] = ny*valid; cp[2] = v; cp[3] = valid;
    }
  }
}

// ---------------- bilinear sample + MLP -> per-(b,k) gaussian params (f32 exact) ----------------
__global__ __launch_bounds__(256) void k_params(const float* __restrict__ x,
                                                const float* __restrict__ rmap,
                                                const float* __restrict__ centers,
                                                const float* __restrict__ w1,
                                                const float* __restrict__ b1,
                                                const float* __restrict__ w2,
                                                const float* __restrict__ b2,
                                                const float* __restrict__ log_alpha,
                                                float* __restrict__ params){
  __shared__ float feat[NC];
  __shared__ float hmid[128];
  __shared__ float pp[4];
  int b = blockIdx.x, tid = threadIdx.x;
  for(int k=0;k<5;k++){
    float cx = centers[(b*5+k)*4+0];
    float cy = centers[(b*5+k)*4+1];
    float valid = centers[(b*5+k)*4+3];
    float px = fminf(fmaxf((cx+1.f)*0.5f*(NW-1), 0.f), (float)(NW-1));
    float py = fminf(fmaxf((cy+1.f)*0.5f*(NH-1), 0.f), (float)(NH-1));
    int x0 = (int)floorf(px); int x1 = min(x0+1, NW-1);
    int y0 = (int)floorf(py); int y1 = min(y0+1, NH-1);
    float wx = px - (float)x0, wy = py - (float)y0;
    {
      const float* xb = x + ((size_t)b*NC + tid)*NHW;
      float v00 = xb[y0*NW+x0], v01 = xb[y0*NW+x1];
      float v10 = xb[y1*NW+x0], v11 = xb[y1*NW+x1];
      feat[tid] = (1.f-wy)*((1.f-wx)*v00 + wx*v01) + wy*((1.f-wx)*v10 + wx*v11);
    }
    __syncthreads();
    if(tid < 128){
      float a = b1[tid];
      for(int c=0;c<NC;c++) a += feat[c]*w1[c*128+tid];
      hmid[tid] = fmaxf(a, 0.f);
    }
    __syncthreads();
    if(tid < 4){
      float a = b2[tid];
      for(int j=0;j<128;j++) a += hmid[j]*w2[j*4+tid];
      pp[tid] = a;
    }
    __syncthreads();
    if(tid == 0){
      const float* rb = rmap + (size_t)b*NHW;
      float r00 = rb[y0*NW+x0], r01 = rb[y0*NW+x1];
      float r10 = rb[y1*NW+x0], r11 = rb[y1*NW+x1];
      float rk = (1.f-wy)*((1.f-wx)*r00 + wx*r01) + wy*((1.f-wx)*r10 + wx*r11);
      float la = log_alpha[0];
      float alpha = logf(1.f + expf(la));
      float dsx = tanhf(pp[0])*0.08f;
      float dsy = tanhf(pp[1])*0.08f;
      float theta = tanhf(pp[2])*3.14159265358979323846f;
      float wgt = 1.f/(1.f + expf(-pp[3]));
      float sx = fminf(fmaxf(alpha*rk + dsx, 0.05f), 0.45f);
      float sy = fminf(fmaxf(alpha*rk*1.5f + dsy, 0.05f), 0.45f);
      float* P = params + (b*5+k)*8;
      P[0] = cx; P[1] = cy;
      P[2] = cosf(theta); P[3] = sinf(theta);
      P[4] = 1.f/(2.f*sx*sx + 1e-6f);
      P[5] = 1.f/(2.f*sy*sy + 1e-6f);
      P[6] = wgt*valid; P[7] = valid;
    }
    __syncthreads();
  }
}

// ---------------- gaussian mixture -> attn (out ch0) ----------------
__global__ __launch_bounds__(256) void k_attn(const float* __restrict__ params,
                                              float* __restrict__ out){
  int tid = threadIdx.x;
  int p = blockIdx.x*256 + tid;
  int b = blockIdx.y;
  int y = p >> 7, x = p & 127;
  float gx = -1.f + 2.f*(float)x/127.f;
  float gy = -1.f + 2.f*(float)y/127.f;
  const float* Pb = params + b*40;
  float wsum = 0.f;
  #pragma unroll
  for(int k=0;k<5;k++) wsum += Pb[k*8+6];
  wsum = fmaxf(wsum, 1e-6f);
  float mix = 0.f;
  #pragma unroll
  for(int k=0;k<5;k++){
    const float* P = Pb + k*8;
    float dx = gx - P[0], dy = gy - P[1];
    float xr =  P[2]*dx + P[3]*dy;
    float yr = -P[3]*dx + P[2]*dy;
    float e = __expf(-(xr*xr*P[4] + yr*yr*P[5]));
    mix += e * (P[6]/wsum);
  }
  float attn = 1.f/(1.f + __expf(-(4.f*mix - 2.f)));
  out[((size_t)(b*2))*NHW + p] = attn;
}

extern "C" void kernel_launch(void* const* d_in, const int* in_sizes, int n_in,
                              void* d_out, int out_size, void* d_ws, size_t ws_size,
                              hipStream_t stream){
  const float* x        = (const float*)d_in[0];
  const float* hm_dw    = (const float*)d_in[1];
  const float* hm_pw1   = (const float*)d_in[2];
  const float* hm_g1    = (const float*)d_in[3];
  const float* hm_b1    = (const float*)d_in[4];
  const float* hm_c3    = (const float*)d_in[5];
  const float* hm_g2    = (const float*)d_in[6];
  const float* hm_b2    = (const float*)d_in[7];
  const float* hm_out_w = (const float*)d_in[8];
  const float* hm_out_b = (const float*)d_in[9];
  const float* r_dw     = (const float*)d_in[10];
  const float* r_pw1    = (const float*)d_in[11];
  const float* r_g      = (const float*)d_in[12];
  const float* r_b      = (const float*)d_in[13];
  const float* r_out_w  = (const float*)d_in[14];
  const float* r_out_b  = (const float*)d_in[15];
  const float* log_alpha= (const float*)d_in[16];
  const float* mlp_w1   = (const float*)d_in[17];
  const float* mlp_b1   = (const float*)d_in[18];
  const float* mlp_w2   = (const float*)d_in[19];
  const float* mlp_b2   = (const float*)d_in[20];
  float* out = (float*)d_out;

  // workspace (~102.2 MB), dwX reused by both branches:
  //   0         : dwX  B8 (B,32,NHW,8) bf16 = 67108864
  //   67108864  : h1   B8 (B,16,NHW,8) bf16 = 33554432
  //   100663296 : heatF (B,NHW) f32         = 524288
  //   101187584 : rmapF (B,NHW) f32         = 524288
  //   101711872 : wT    (9,128,128) bf16    = 294912
  //   102006784 : wPW1h (128,256) bf16      = 65536
  //   102072320 : wPW1r (64,256) bf16       = 32768
  //   102105088 : tsv / tsi / centers / params
  char* ws = (char*)d_ws;
  bf16*  dwX     = (bf16*)ws;
  bf16*  h1      = (bf16*)(ws + 67108864);
  float* heatF   = (float*)(ws + 100663296);
  float* rmapF   = (float*)(ws + 101187584);
  bf16*  wT      = (bf16*)(ws + 101711872);
  bf16*  wPW1h   = (bf16*)(ws + 102006784);
  bf16*  wPW1r   = (bf16*)(ws + 102072320);
  float* tsv     = (float*)(ws + 102105088);
  int*   tsi     = (int*)  (ws + 102110208);
  float* centers = (float*)(ws + 102115328);
  float* params  = (float*)(ws + 102115968);

  // weight prep (tiny)
  k_cvt  <<<dim3(128), dim3(256), 0, stream>>>(hm_pw1, wPW1h, 128*256);
  k_cvt  <<<dim3(64),  dim3(256), 0, stream>>>(r_pw1,  wPW1r, 64*256);
  k_trans<<<dim3(576), dim3(256), 0, stream>>>(hm_c3, wT);

  // radius branch first (dwX reused afterwards by heat branch)
  k_dwb<<<dim3(16, 32, NB), dim3(256), 0, stream>>>(x, r_dw, dwX);
  k_pw<4,1><<<dim3(2048), dim3(256), 0, stream>>>(dwX, wPW1r, r_g, r_b,
                                                  r_out_w, r_out_b,
                                                  (bf16*)nullptr, rmapF);
  // heat branch
  k_dwb<<<dim3(16, 32, NB), dim3(256), 0, stream>>>(x, hm_dw, dwX);
  k_pw<8,0><<<dim3(2048), dim3(256), 0, stream>>>(dwX, wPW1h, hm_g1, hm_b1,
                                                  (const float*)nullptr, (const float*)nullptr,
                                                  h1, (float*)nullptr);
  // c3 + heat head (full-row blocks)
  k_c3<<<dim3(128, NB), dim3(256), 0, stream>>>(h1, wT, hm_g2, hm_b2, hm_out_w, hm_out_b, heatF, out);
  // topk (2-stage) -> centers; params; attn
  k_topk1<<<dim3(32, NB), dim3(256), 0, stream>>>(heatF, tsv, tsi);
  k_topk2<<<dim3(NB), dim3(256), 0, stream>>>(tsv, tsi, centers);
  k_params<<<dim3(NB), dim3(256), 0, stream>>>(x, rmapF, centers, mlp_w1, mlp_b1, mlp_w2, mlp_b2, log_alpha, params);
  k_attn<<<dim3(64, NB), dim3(256), 0, stream>>>(params, out);
}

// Round 6
// 704.683 us; speedup vs baseline: 1.1639x; 1.1639x over previous
//
#include <hip/hip_runtime.h>
#include <hip/hip_bf16.h>
#include <math.h>

typedef __hip_bfloat16 bf16;
using short8 = __attribute__((ext_vector_type(8))) short;
using f32x4  = __attribute__((ext_vector_type(4))) float;

#define NB 8
#define NC 256
#define NH 128
#define NW 128
#define NHW 16384
#define MID 128
#define HP 130           /* padded plane dim */
#define HPP (HP*HP)      /* 16900 */

__device__ __forceinline__ float b2f(bf16 v){ return __bfloat162float(v); }
__device__ __forceinline__ bf16 f2b(float v){ return __float2bfloat16(v); }
#define BN_S 0.9999950000374997f  /* 1/sqrt(1+1e-5) */

// ---------------- f32 -> bf16 weight convert ----------------
__global__ __launch_bounds__(256) void k_cvt(const float* __restrict__ src, bf16* __restrict__ dst, int n){
  int i = blockIdx.x*256 + threadIdx.x;
  if(i < n) dst[i] = f2b(src[i]);
}

// ---------------- hm_c3 (m,c,3,3) f32 -> (tau,m,c) bf16 ----------------
__global__ __launch_bounds__(256) void k_trans(const float* __restrict__ src, bf16* __restrict__ dst){
  int i = blockIdx.x*256 + threadIdx.x;
  if(i >= MID*MID*9) return;
  int tau = i % 9; int c = (i/9) % MID; int m = i/(9*MID);
  dst[((size_t)tau*MID + m)*MID + c] = f2b(src[i]);
}

// ---------------- zero 1-px border of padded h1 planes ----------------
__global__ __launch_bounds__(256) void k_zero(bf16* __restrict__ h1p){
  int s = blockIdx.x*256 + threadIdx.x;
  const int NPLANE = NB*16;
  const int PER = 2*HP + 2*(HP-2);     // 516
  if(s >= NPLANE*PER) return;
  int plane = s / PER, j = s % PER;
  int px;
  if(j < HP)            px = j;                          // row 0
  else if(j < 2*HP)     px = 129*HP + (j - HP);          // row 129
  else if(j < 2*HP+128) px = (j - 2*HP + 1)*HP;          // col 0
  else                  px = (j - (2*HP+128) + 1)*HP + 129; // col 129
  short8 z = {0,0,0,0,0,0,0,0};
  *(short8*)((ushort*)h1p + ((size_t)plane*HPP + px)*8) = z;
}

// ============ depthwise 3x3 pad=1: f32 NCHW in -> bf16 channel-blocked (B8) out ============
// out: [b][g=ch/8][pixel][8ch]; grid (16 row-tiles, 32 ch-groups, B)
// thread t owns 4 CONSECUTIVE cols -> coalesced 64B stores
__global__ __launch_bounds__(256) void k_dwb(const float* __restrict__ x,
                                             const float* __restrict__ w9,
                                             bf16* __restrict__ outB8){
  __shared__ float tile[8][10][136];   // data cols at [4..131]; borders [3] and [132] zeroed
  int tid = threadIdx.x;
  int cg = blockIdx.y, b = blockIdx.z;
  int y0 = blockIdx.x*8;
  // stage 8 ch x 10 rows x 32 float4 (aligned stores at col offset 4)
  #pragma unroll
  for(int it=0; it<10; it++){
    int idx = it*256 + tid;
    int c = idx / 320, rem = idx % 320;
    int row = rem >> 5, col4 = rem & 31;
    int gy = y0 - 1 + row;
    float4 v = make_float4(0.f,0.f,0.f,0.f);
    if(gy >= 0 && gy < NH)
      v = *(const float4*)(x + ((size_t)(b*NC + cg*8 + c))*NHW + gy*NW + col4*4);
    *(float4*)&tile[c][row][4 + col4*4] = v;
  }
  if(tid < 160){
    int c = tid/20, rem = tid%20;
    int row = rem>>1;
    tile[c][row][(rem&1) ? 132 : 3] = 0.f;
  }
  __syncthreads();
  int row = tid >> 5;        // 0..7
  int t   = tid & 31;        // cols 4t..4t+3
  union { ushort u[8]; short8 v; } o[4];
  for(int c=0;c<8;c++){
    float wf[9];
    #pragma unroll
    for(int i=0;i<9;i++) wf[i] = w9[(cg*8+c)*9 + i];
    float a0=0.f, a1=0.f, a2=0.f, a3=0.f;
    #pragma unroll
    for(int dr=0;dr<3;dr++){
      float f0 = tile[c][row+dr][3 + 4*t];
      float4 v4 = *(const float4*)&tile[c][row+dr][4 + 4*t];
      float f5 = tile[c][row+dr][8 + 4*t];
      float w0 = wf[dr*3+0], w1 = wf[dr*3+1], w2 = wf[dr*3+2];
      a0 += f0*w0   + v4.x*w1 + v4.y*w2;
      a1 += v4.x*w0 + v4.y*w1 + v4.z*w2;
      a2 += v4.y*w0 + v4.z*w1 + v4.w*w2;
      a3 += v4.z*w0 + v4.w*w1 + f5*w2;
    }
    bf16 q0=f2b(a0), q1=f2b(a1), q2=f2b(a2), q3=f2b(a3);
    o[0].u[c]=*(ushort*)&q0; o[1].u[c]=*(ushort*)&q1;
    o[2].u[c]=*(ushort*)&q2; o[3].u[c]=*(ushort*)&q3;
  }
  size_t base = ((size_t)(b*32+cg))*NHW + (y0+row)*NW + 4*t;
  #pragma unroll
  for(int i=0;i<4;i++) *(short8*)(outB8 + (base+i)*8) = o[i].v;
}

// ============ pointwise GEMM (B8 in, K=256) + bn/relu + epilogue; no LDS/barriers ============
// MODE 0: write M=128 channels into PADDED h1 (B8-16 planes); MODE 1: radius head -> rmapF
template<int MT, int MODE>
__global__ __launch_bounds__(256) void k_pw(const bf16* __restrict__ in8,   // (B,32,NHW,8)
                                            const bf16* __restrict__ wA,    // (M,256)
                                            const float* __restrict__ g,
                                            const float* __restrict__ bias,
                                            const float* __restrict__ hw,
                                            const float* __restrict__ hb,
                                            bf16*  __restrict__ h1p,        // padded (B,16,HPP,8)
                                            float* __restrict__ outMap){
  int tid = threadIdx.x;
  int bidx = blockIdx.x;
  int b = bidx >> 8;
  int p0 = (bidx & 255)*64;
  int lane = tid & 63, wave = tid >> 6;
  int n = lane & 15, quad = lane >> 4;
  size_t pix = p0 + wave*16 + n;
  const ushort* inU = (const ushort*)in8;
  const ushort* wU  = (const ushort*)wA;

  f32x4 acc[MT];
  #pragma unroll
  for(int i=0;i<MT;i++){
    #pragma unroll
    for(int r=0;r<4;r++) acc[i][r] = 0.f;
  }
  #pragma unroll
  for(int k0=0;k0<NC;k0+=32){
    short8 bfrag = *(const short8*)&inU[ (((size_t)(b*32) + (k0>>3) + quad)*NHW + pix)*8 ];
    #pragma unroll
    for(int mt=0;mt<MT;mt++){
      short8 afrag = *(const short8*)&wU[(size_t)(mt*16 + n)*NC + k0 + quad*8];
      acc[mt] = __builtin_amdgcn_mfma_f32_16x16x32_bf16(afrag, bfrag, acc[mt], 0, 0, 0);
    }
  }

  if(MODE == 0){
    int py = ((int)(pix>>7) + 1)*HP + (int)(pix&127) + 1;
    #pragma unroll
    for(int mt=0;mt<MT;mt++){
      int mg  = mt*2 + (quad>>1);
      int off = (quad&1)*4;
      union { ushort u[4]; ushort4 v; } t;
      #pragma unroll
      for(int r=0;r<4;r++){
        int m = mt*16 + quad*4 + r;
        float v = acc[mt][r]*(g[m]*BN_S) + bias[m];
        bf16 ab = f2b(fmaxf(v, 0.f));
        t.u[r] = *(ushort*)&ab;
      }
      *(ushort4*)((ushort*)h1p + (((size_t)(b*16+mg))*HPP + py)*8 + off) = t.v;
    }
  }else{
    float ph = 0.f;
    #pragma unroll
    for(int mt=0;mt<MT;mt++){
      #pragma unroll
      for(int r=0;r<4;r++){
        int m = mt*16 + quad*4 + r;
        float v = acc[mt][r]*(g[m]*BN_S) + bias[m];
        ph += fmaxf(v, 0.f) * hw[m];
      }
    }
    ph += __shfl_xor(ph, 16);
    ph += __shfl_xor(ph, 32);
    if(lane < 16){
      float sg = 1.f/(1.f + expf(-(ph + hb[0])));
      outMap[(size_t)b*NHW + pix] = 0.03f + sg*0.37f;
    }
  }
}

// ============ 3x3 conv MID->MID on padded h1; branchless; + bn/relu + heat head ============
// block = full row (128 px); wave: 2 n-groups x 8 m-tiles
__global__ __launch_bounds__(256) void k_c3(const bf16* __restrict__ h1p,   // (B,16,HPP,8)
                                            const bf16* __restrict__ wT,    // (tau,m,c)
                                            const float* __restrict__ g,
                                            const float* __restrict__ bias,
                                            const float* __restrict__ hw,
                                            const float* __restrict__ hb,
                                            float* __restrict__ heatF,
                                            float* __restrict__ out){
  int tid = threadIdx.x;
  int y = blockIdx.x, b = blockIdx.y;
  int lane = tid & 63, wave = tid >> 6;
  int n = lane & 15, quad = lane >> 4;
  const ushort* inU = (const ushort*)h1p;
  const ushort* wU  = (const ushort*)wT;
  f32x4 acc[8][2];
  #pragma unroll
  for(int i=0;i<8;i++){
    #pragma unroll
    for(int j=0;j<2;j++){
      #pragma unroll
      for(int r=0;r<4;r++) acc[i][j][r] = 0.f;
    }
  }
  int colbase = wave*32 + n;   // unpadded col of ng=0; padded col = colbase + dx
  for(int dy=0;dy<3;dy++){
    #pragma unroll
    for(int dx=0;dx<3;dx++){
      const ushort* wtb = wU + (size_t)(dy*3+dx)*MID*MID;
      #pragma unroll
      for(int k0=0;k0<MID;k0+=32){
        size_t base = ((size_t)(b*16) + (k0>>3) + quad)*HPP + (size_t)(y+dy)*HP + colbase + dx;
        short8 b0 = *(const short8*)&inU[base*8];
        short8 b1 = *(const short8*)&inU[(base+16)*8];
        #pragma unroll
        for(int mt=0;mt<8;mt++){
          short8 a = *(const short8*)&wtb[(size_t)(mt*16 + n)*MID + k0 + quad*8];
          acc[mt][0] = __builtin_amdgcn_mfma_f32_16x16x32_bf16(a, b0, acc[mt][0], 0, 0, 0);
          acc[mt][1] = __builtin_amdgcn_mfma_f32_16x16x32_bf16(a, b1, acc[mt][1], 0, 0, 0);
        }
      }
    }
  }
  #pragma unroll
  for(int ng=0;ng<2;ng++){
    float ph = 0.f;
    #pragma unroll
    for(int mt=0;mt<8;mt++){
      #pragma unroll
      for(int r=0;r<4;r++){
        int m = mt*16 + quad*4 + r;
        float v = acc[mt][ng][r]*(g[m]*BN_S) + bias[m];
        ph += fmaxf(v, 0.f) * hw[m];
      }
    }
    ph += __shfl_xor(ph, 16);
    ph += __shfl_xor(ph, 32);
    if(lane < 16){
      int pix = y*NW + wave*32 + ng*16 + lane;
      float sg = 1.f/(1.f + expf(-(ph + hb[0])));
      heatF[(size_t)b*NHW + pix] = sg;
      out[((size_t)(b*2+1))*NHW + pix] = sg;
    }
  }
}

// ---------------- topk stage 1: per-512px-block top-5 ----------------
__global__ __launch_bounds__(256) void k_topk1(const float* __restrict__ heat,
                                               float* __restrict__ sv_g,
                                               int*   __restrict__ si_g){
  __shared__ float sv[256*5];
  __shared__ int   si[256*5];
  int blk = blockIdx.x, b = blockIdx.y, tid = threadIdx.x;
  const float* hb = heat + (size_t)b*NHW;
  float tv[5]; int ti[5];
  #pragma unroll
  for(int i=0;i<5;i++){ tv[i] = -1.f; ti[i] = 0x7fffffff; }
  for(int s=0;s<2;s++){
    int p = blk*512 + s*256 + tid;
    int y = p >> 7, x = p & 127;
    float v = hb[p];
    float mx = v;
    for(int dy=-1;dy<=1;dy++){
      int yy = y+dy; if(yy<0||yy>=NH) continue;
      for(int dx=-1;dx<=1;dx++){
        int xc = x+dx; if(xc<0||xc>=NW) continue;
        mx = fmaxf(mx, hb[yy*NW+xc]);
      }
    }
    float pv = (v == mx) ? v : 0.f;
    #pragma unroll
    for(int j=0;j<5;j++){
      if(pv > tv[j] || (pv == tv[j] && p < ti[j])){
        for(int q=4;q>j;q--){ tv[q]=tv[q-1]; ti[q]=ti[q-1]; }
        tv[j] = pv; ti[j] = p;
        break;
      }
    }
  }
  #pragma unroll
  for(int i=0;i<5;i++){ sv[tid*5+i] = tv[i]; si[tid*5+i] = ti[i]; }
  __syncthreads();
  if(tid < 64){
    float mv[5]; int mi[5];
    #pragma unroll
    for(int i=0;i<5;i++){ mv[i] = -1.f; mi[i] = 0x7fffffff; }
    for(int s=0;s<4;s++){
      int t2 = tid + s*64;
      for(int i=0;i<5;i++){
        float pv = sv[t2*5+i]; int pi = si[t2*5+i];
        for(int j=0;j<5;j++){
          if(pv > mv[j] || (pv == mv[j] && pi < mi[j])){
            for(int q=4;q>j;q--){ mv[q]=mv[q-1]; mi[q]=mi[q-1]; }
            mv[j] = pv; mi[j] = pi;
            break;
          }
        }
      }
    }
    for(int i=0;i<5;i++){ sv[tid*5+i] = mv[i]; si[tid*5+i] = mi[i]; }
  }
  __syncthreads();
  if(tid == 0){
    float fv[5]; int fi[5];
    #pragma unroll
    for(int i=0;i<5;i++){ fv[i] = -1.f; fi[i] = 0x7fffffff; }
    for(int t2=0;t2<64;t2++){
      for(int i=0;i<5;i++){
        float pv = sv[t2*5+i]; int pi = si[t2*5+i];
        for(int j=0;j<5;j++){
          if(pv > fv[j] || (pv == fv[j] && pi < fi[j])){
            for(int q=4;q>j;q--){ fv[q]=fv[q-1]; fi[q]=fi[q-1]; }
            fv[j] = pv; fi[j] = pi;
            break;
          }
        }
      }
    }
    for(int i=0;i<5;i++){
      sv_g[(b*32 + blk)*5 + i] = fv[i];
      si_g[(b*32 + blk)*5 + i] = fi[i];
    }
  }
}

// ---------------- topk stage 2: rank-select over 160 candidates -> centers ----------------
__global__ __launch_bounds__(256) void k_topk2(const float* __restrict__ sv_g,
                                               const int*   __restrict__ si_g,
                                               float* __restrict__ centers){
  __shared__ float cv[160];
  __shared__ int   ci[160];
  int b = blockIdx.x, tid = threadIdx.x;
  if(tid < 160){ cv[tid] = sv_g[b*160 + tid]; ci[tid] = si_g[b*160 + tid]; }
  __syncthreads();
  if(tid < 160){
    float v = cv[tid]; int idx = ci[tid];
    int rank = 0;
    for(int j=0;j<160;j++){
      float vj = cv[j]; int ij = ci[j];
      rank += (vj > v || (vj == v && ij < idx)) ? 1 : 0;
    }
    if(rank < 5){
      float valid = (v >= 0.1f) ? 1.f : 0.f;
      float row = (float)(idx >> 7);
      float col = (float)(idx & 127);
      float ny = 2.f*row/127.f - 1.f;
      float nx = 2.f*col/127.f - 1.f;
      float* cp = centers + (b*5+rank)*4;
      cp[0] = nx*valid; cp[1] = ny*valid; cp[2] = v; cp[3] = valid;
    }
  }
}

// ---------------- per-(b,k): bilinear sample + MLP -> gaussian params (f32 exact) ----------------
__global__ __launch_bounds__(256) void k_params(const float* __restrict__ x,
                                                const float* __restrict__ rmap,
                                                const float* __restrict__ centers,
                                                const float* __restrict__ w1,
                                                const float* __restrict__ b1,
                                                const float* __restrict__ w2,
                                                const float* __restrict__ b2,
                                                const float* __restrict__ log_alpha,
                                                float* __restrict__ params){
  __shared__ float feat[NC];
  __shared__ float hmid[128];
  __shared__ float pp[4];
  int bk = blockIdx.x;
  int b = bk/5;
  int tid = threadIdx.x;
  float cx = centers[bk*4+0];
  float cy = centers[bk*4+1];
  float valid = centers[bk*4+3];
  float px = fminf(fmaxf((cx+1.f)*0.5f*(NW-1), 0.f), (float)(NW-1));
  float py = fminf(fmaxf((cy+1.f)*0.5f*(NH-1), 0.f), (float)(NH-1));
  int x0 = (int)floorf(px); int x1 = min(x0+1, NW-1);
  int y0 = (int)floorf(py); int y1 = min(y0+1, NH-1);
  float wx = px - (float)x0, wy = py - (float)y0;
  {
    const float* xb = x + ((size_t)b*NC + tid)*NHW;
    float v00 = xb[y0*NW+x0], v01 = xb[y0*NW+x1];
    float v10 = xb[y1*NW+x0], v11 = xb[y1*NW+x1];
    feat[tid] = (1.f-wy)*((1.f-wx)*v00 + wx*v01) + wy*((1.f-wx)*v10 + wx*v11);
  }
  __syncthreads();
  if(tid < 128){
    float a = b1[tid];
    for(int c=0;c<NC;c++) a += feat[c]*w1[c*128+tid];
    hmid[tid] = fmaxf(a, 0.f);
  }
  __syncthreads();
  if(tid < 4){
    float a = b2[tid];
    for(int j=0;j<128;j++) a += hmid[j]*w2[j*4+tid];
    pp[tid] = a;
  }
  __syncthreads();
  if(tid == 0){
    const float* rb = rmap + (size_t)b*NHW;
    float r00 = rb[y0*NW+x0], r01 = rb[y0*NW+x1];
    float r10 = rb[y1*NW+x0], r11 = rb[y1*NW+x1];
    float rk = (1.f-wy)*((1.f-wx)*r00 + wx*r01) + wy*((1.f-wx)*r10 + wx*r11);
    float la = log_alpha[0];
    float alpha = logf(1.f + expf(la));
    float dsx = tanhf(pp[0])*0.08f;
    float dsy = tanhf(pp[1])*0.08f;
    float theta = tanhf(pp[2])*3.14159265358979323846f;
    float wgt = 1.f/(1.f + expf(-pp[3]));
    float sx = fminf(fmaxf(alpha*rk + dsx, 0.05f), 0.45f);
    float sy = fminf(fmaxf(alpha*rk*1.5f + dsy, 0.05f), 0.45f);
    float* P = params + bk*8;
    P[0] = cx; P[1] = cy;
    P[2] = cosf(theta); P[3] = sinf(theta);
    P[4] = 1.f/(2.f*sx*sx + 1e-6f);
    P[5] = 1.f/(2.f*sy*sy + 1e-6f);
    P[6] = wgt*valid; P[7] = valid;
  }
}

// ---------------- gaussian mixture -> attn (out ch0) ----------------
__global__ __launch_bounds__(256) void k_attn(const float* __restrict__ params,
                                              float* __restrict__ out){
  int tid = threadIdx.x;
  int p = blockIdx.x*256 + tid;
  int b = blockIdx.y;
  int y = p >> 7, x = p & 127;
  float gx = -1.f + 2.f*(float)x/127.f;
  float gy = -1.f + 2.f*(float)y/127.f;
  const float* Pb = params + b*40;
  float wsum = 0.f;
  #pragma unroll
  for(int k=0;k<5;k++) wsum += Pb[k*8+6];
  wsum = fmaxf(wsum, 1e-6f);
  float mix = 0.f;
  #pragma unroll
  for(int k=0;k<5;k++){
    const float* P = Pb + k*8;
    float dx = gx - P[0], dy = gy - P[1];
    float xr =  P[2]*dx + P[3]*dy;
    float yr = -P[3]*dx + P[2]*dy;
    float e = __expf(-(xr*xr*P[4] + yr*yr*P[5]));
    mix += e * (P[6]/wsum);
  }
  float attn = 1.f/(1.f + __expf(-(4.f*mix - 2.f)));
  out[((size_t)(b*2))*NHW + p] = attn;
}

extern "C" void kernel_launch(void* const* d_in, const int* in_sizes, int n_in,
                              void* d_out, int out_size, void* d_ws, size_t ws_size,
                              hipStream_t stream){
  const float* x        = (const float*)d_in[0];
  const float* hm_dw    = (const float*)d_in[1];
  const float* hm_pw1   = (const float*)d_in[2];
  const float* hm_g1    = (const float*)d_in[3];
  const float* hm_b1    = (const float*)d_in[4];
  const float* hm_c3    = (const float*)d_in[5];
  const float* hm_g2    = (const float*)d_in[6];
  const float* hm_b2    = (const float*)d_in[7];
  const float* hm_out_w = (const float*)d_in[8];
  const float* hm_out_b = (const float*)d_in[9];
  const float* r_dw     = (const float*)d_in[10];
  const float* r_pw1    = (const float*)d_in[11];
  const float* r_g      = (const float*)d_in[12];
  const float* r_b      = (const float*)d_in[13];
  const float* r_out_w  = (const float*)d_in[14];
  const float* r_out_b  = (const float*)d_in[15];
  const float* log_alpha= (const float*)d_in[16];
  const float* mlp_w1   = (const float*)d_in[17];
  const float* mlp_b1   = (const float*)d_in[18];
  const float* mlp_w2   = (const float*)d_in[19];
  const float* mlp_b2   = (const float*)d_in[20];
  float* out = (float*)d_out;

  // workspace (~103.2 MB):
  //   0         : dwX  B8 (B,32,NHW,8) bf16     = 67108864
  //   67108864  : h1p padded (B,16,HPP,8) bf16  = 34611200
  //   101720064 : heatF (B,NHW) f32             = 524288
  //   102244352 : rmapF (B,NHW) f32             = 524288
  //   102768640 : wT (9,128,128) bf16           = 294912
  //   103063552 : wPW1h (128,256) bf16          = 65536
  //   103129088 : wPW1r (64,256) bf16           = 32768
  //   103161856 : tsv / 103166976: tsi / 103172096: centers / 103172736: params
  char* ws = (char*)d_ws;
  bf16*  dwX     = (bf16*)ws;
  bf16*  h1p     = (bf16*)(ws + 67108864);
  float* heatF   = (float*)(ws + 101720064);
  float* rmapF   = (float*)(ws + 102244352);
  bf16*  wT      = (bf16*)(ws + 102768640);
  bf16*  wPW1h   = (bf16*)(ws + 103063552);
  bf16*  wPW1r   = (bf16*)(ws + 103129088);
  float* tsv     = (float*)(ws + 103161856);
  int*   tsi     = (int*)  (ws + 103166976);
  float* centers = (float*)(ws + 103172096);
  float* params  = (float*)(ws + 103172736);

  // prep (tiny)
  k_cvt  <<<dim3(128), dim3(256), 0, stream>>>(hm_pw1, wPW1h, 128*256);
  k_cvt  <<<dim3(64),  dim3(256), 0, stream>>>(r_pw1,  wPW1r, 64*256);
  k_trans<<<dim3(576), dim3(256), 0, stream>>>(hm_c3, wT);
  k_zero <<<dim3((NB*16*516 + 255)/256), dim3(256), 0, stream>>>(h1p);

  // radius branch first (dwX reused afterwards by heat branch)
  k_dwb<<<dim3(16, 32, NB), dim3(256), 0, stream>>>(x, r_dw, dwX);
  k_pw<4,1><<<dim3(2048), dim3(256), 0, stream>>>(dwX, wPW1r, r_g, r_b,
                                                  r_out_w, r_out_b,
                                                  (bf16*)nullptr, rmapF);
  // heat branch
  k_dwb<<<dim3(16, 32, NB), dim3(256), 0, stream>>>(x, hm_dw, dwX);
  k_pw<8,0><<<dim3(2048), dim3(256), 0, stream>>>(dwX, wPW1h, hm_g1, hm_b1,
                                                  (const float*)nullptr, (const float*)nullptr,
                                                  h1p, (float*)nullptr);
  // c3 + heat head
  k_c3<<<dim3(128, NB), dim3(256), 0, stream>>>(h1p, wT, hm_g2, hm_b2, hm_out_w, hm_out_b, heatF, out);
  // topk -> centers; params (40 blocks); attn
  k_topk1<<<dim3(32, NB), dim3(256), 0, stream>>>(heatF, tsv, tsi);
  k_topk2<<<dim3(NB), dim3(256), 0, stream>>>(tsv, tsi, centers);
  k_params<<<dim3(NB*5), dim3(256), 0, stream>>>(x, rmapF, centers, mlp_w1, mlp_b1, mlp_w2, mlp_b2, log_alpha, params);
  k_attn<<<dim3(64, NB), dim3(256), 0, stream>>>(params, out);
}

// Round 7
// 638.492 us; speedup vs baseline: 1.2846x; 1.1037x over previous
//
#include <hip/hip_runtime.h>
#include <hip/hip_bf16.h>
#include <math.h>

typedef __hip_bfloat16 bf16;
using short8 = __attribute__((ext_vector_type(8))) short;
using f32x4  = __attribute__((ext_vector_type(4))) float;

#define NB 8
#define NC 256
#define NH 128
#define NW 128
#define NHW 16384
#define MID 128
#define HP 130
#define HPP (HP*HP)

__device__ __forceinline__ float b2f(bf16 v){ return __bfloat162float(v); }
__device__ __forceinline__ bf16 f2b(float v){ return __float2bfloat16(v); }
#define BN_S 0.9999950000374997f  /* 1/sqrt(1+1e-5) */

// ---------------- f32 -> bf16 weight convert ----------------
__global__ __launch_bounds__(256) void k_cvt(const float* __restrict__ src, bf16* __restrict__ dst, int n){
  int i = blockIdx.x*256 + threadIdx.x;
  if(i < n) dst[i] = f2b(src[i]);
}

// ---------------- hm_c3 (m,c,3,3) f32 -> (tau,m,c) bf16 ----------------
__global__ __launch_bounds__(256) void k_trans(const float* __restrict__ src, bf16* __restrict__ dst){
  int i = blockIdx.x*256 + threadIdx.x;
  if(i >= MID*MID*9) return;
  int tau = i % 9; int c = (i/9) % MID; int m = i/(9*MID);
  dst[((size_t)tau*MID + m)*MID + c] = f2b(src[i]);
}

// ---------------- zero 1-px border of padded h1 planes ----------------
__global__ __launch_bounds__(256) void k_zero(bf16* __restrict__ h1p){
  int s = blockIdx.x*256 + threadIdx.x;
  const int NPLANE = NB*16;
  const int PER = 2*HP + 2*(HP-2);     // 516
  if(s >= NPLANE*PER) return;
  int plane = s / PER, j = s % PER;
  int px;
  if(j < HP)            px = j;
  else if(j < 2*HP)     px = 129*HP + (j - HP);
  else if(j < 2*HP+128) px = (j - 2*HP + 1)*HP;
  else                  px = (j - (2*HP+128) + 1)*HP + 129;
  short8 z = {0,0,0,0,0,0,0,0};
  *(short8*)((ushort*)h1p + ((size_t)plane*HPP + px)*8) = z;
}

// ============ depthwise 3x3, SINGLE weight set ============
__global__ __launch_bounds__(256) void k_dwb(const float* __restrict__ x,
                                             const float* __restrict__ w9,
                                             bf16* __restrict__ outB8){
  __shared__ float tile[8][10][136];
  int tid = threadIdx.x;
  int cg = blockIdx.y, b = blockIdx.z;
  int y0 = blockIdx.x*8;
  #pragma unroll
  for(int it=0; it<10; it++){
    int idx = it*256 + tid;
    int c = idx / 320, rem = idx % 320;
    int row = rem >> 5, col4 = rem & 31;
    int gy = y0 - 1 + row;
    float4 v = make_float4(0.f,0.f,0.f,0.f);
    if(gy >= 0 && gy < NH)
      v = *(const float4*)(x + ((size_t)(b*NC + cg*8 + c))*NHW + gy*NW + col4*4);
    *(float4*)&tile[c][row][4 + col4*4] = v;
  }
  if(tid < 160){
    int c = tid/20, rem = tid%20;
    int row = rem>>1;
    tile[c][row][(rem&1) ? 132 : 3] = 0.f;
  }
  __syncthreads();
  int row = tid >> 5;
  int t   = tid & 31;
  union { ushort u[8]; short8 v; } o[4];
  for(int c=0;c<8;c++){
    float wf[9];
    #pragma unroll
    for(int i=0;i<9;i++) wf[i] = w9[(cg*8+c)*9 + i];
    float a0=0.f, a1=0.f, a2=0.f, a3=0.f;
    #pragma unroll
    for(int dr=0;dr<3;dr++){
      float f0 = tile[c][row+dr][3 + 4*t];
      float4 v4 = *(const float4*)&tile[c][row+dr][4 + 4*t];
      float f5 = tile[c][row+dr][8 + 4*t];
      float w0 = wf[dr*3+0], w1 = wf[dr*3+1], w2 = wf[dr*3+2];
      a0 += f0*w0   + v4.x*w1 + v4.y*w2;
      a1 += v4.x*w0 + v4.y*w1 + v4.z*w2;
      a2 += v4.y*w0 + v4.z*w1 + v4.w*w2;
      a3 += v4.z*w0 + v4.w*w1 + f5*w2;
    }
    bf16 q0=f2b(a0), q1=f2b(a1), q2=f2b(a2), q3=f2b(a3);
    o[0].u[c]=*(ushort*)&q0; o[1].u[c]=*(ushort*)&q1;
    o[2].u[c]=*(ushort*)&q2; o[3].u[c]=*(ushort*)&q3;
  }
  size_t base = ((size_t)(b*32+cg))*NHW + (y0+row)*NW + 4*t;
  #pragma unroll
  for(int i=0;i<4;i++) *(short8*)(outB8 + (base+i)*8) = o[i].v;
}

// ============ depthwise 3x3, DUAL weight set (stages x once) ============
__global__ __launch_bounds__(256) void k_dwb2(const float* __restrict__ x,
                                              const float* __restrict__ wA9,
                                              const float* __restrict__ wB9,
                                              bf16* __restrict__ outA,
                                              bf16* __restrict__ outB){
  __shared__ float tile[8][10][136];
  int tid = threadIdx.x;
  int cg = blockIdx.y, b = blockIdx.z;
  int y0 = blockIdx.x*8;
  #pragma unroll
  for(int it=0; it<10; it++){
    int idx = it*256 + tid;
    int c = idx / 320, rem = idx % 320;
    int row = rem >> 5, col4 = rem & 31;
    int gy = y0 - 1 + row;
    float4 v = make_float4(0.f,0.f,0.f,0.f);
    if(gy >= 0 && gy < NH)
      v = *(const float4*)(x + ((size_t)(b*NC + cg*8 + c))*NHW + gy*NW + col4*4);
    *(float4*)&tile[c][row][4 + col4*4] = v;
  }
  if(tid < 160){
    int c = tid/20, rem = tid%20;
    int row = rem>>1;
    tile[c][row][(rem&1) ? 132 : 3] = 0.f;
  }
  __syncthreads();
  int row = tid >> 5;
  int t   = tid & 31;
  union { ushort u[8]; short8 v; } oA[4], oB[4];
  for(int c=0;c<8;c++){
    float wfA[9], wfB[9];
    #pragma unroll
    for(int i=0;i<9;i++){ wfA[i] = wA9[(cg*8+c)*9 + i]; wfB[i] = wB9[(cg*8+c)*9 + i]; }
    float aA0=0.f,aA1=0.f,aA2=0.f,aA3=0.f;
    float aB0=0.f,aB1=0.f,aB2=0.f,aB3=0.f;
    #pragma unroll
    for(int dr=0;dr<3;dr++){
      float f0 = tile[c][row+dr][3 + 4*t];
      float4 v4 = *(const float4*)&tile[c][row+dr][4 + 4*t];
      float f5 = tile[c][row+dr][8 + 4*t];
      float wa0=wfA[dr*3+0], wa1=wfA[dr*3+1], wa2=wfA[dr*3+2];
      float wb0=wfB[dr*3+0], wb1=wfB[dr*3+1], wb2=wfB[dr*3+2];
      aA0 += f0*wa0   + v4.x*wa1 + v4.y*wa2;
      aA1 += v4.x*wa0 + v4.y*wa1 + v4.z*wa2;
      aA2 += v4.y*wa0 + v4.z*wa1 + v4.w*wa2;
      aA3 += v4.z*wa0 + v4.w*wa1 + f5*wa2;
      aB0 += f0*wb0   + v4.x*wb1 + v4.y*wb2;
      aB1 += v4.x*wb0 + v4.y*wb1 + v4.z*wb2;
      aB2 += v4.y*wb0 + v4.z*wb1 + v4.w*wb2;
      aB3 += v4.z*wb0 + v4.w*wb1 + f5*wb2;
    }
    bf16 q;
    q=f2b(aA0); oA[0].u[c]=*(ushort*)&q;  q=f2b(aA1); oA[1].u[c]=*(ushort*)&q;
    q=f2b(aA2); oA[2].u[c]=*(ushort*)&q;  q=f2b(aA3); oA[3].u[c]=*(ushort*)&q;
    q=f2b(aB0); oB[0].u[c]=*(ushort*)&q;  q=f2b(aB1); oB[1].u[c]=*(ushort*)&q;
    q=f2b(aB2); oB[2].u[c]=*(ushort*)&q;  q=f2b(aB3); oB[3].u[c]=*(ushort*)&q;
  }
  size_t base = ((size_t)(b*32+cg))*NHW + (y0+row)*NW + 4*t;
  #pragma unroll
  for(int i=0;i<4;i++){
    *(short8*)(outA + (base+i)*8) = oA[i].v;
    *(short8*)(outB + (base+i)*8) = oB[i].v;
  }
}

// ============ pointwise GEMM (B8 in, K=256): wave = 32px x 64ch ============
// MODE 0: write 64 channels (Moff = 64*blockIdx.y) into padded h1; MODE 1: radius head
template<int MODE>
__global__ __launch_bounds__(256) void k_pw(const bf16* __restrict__ in8,
                                            const bf16* __restrict__ wA,    // (M,256)
                                            const float* __restrict__ g,
                                            const float* __restrict__ bias,
                                            const float* __restrict__ hw,
                                            const float* __restrict__ hb,
                                            bf16*  __restrict__ h1p,
                                            float* __restrict__ outMap){
  int tid = threadIdx.x;
  int bidx = blockIdx.x;
  int b = bidx >> 7;
  int p0 = (bidx & 127)*128;
  int Moff = blockIdx.y*64;
  int lane = tid & 63, wave = tid >> 6;
  int n = lane & 15, quad = lane >> 4;
  size_t pix0 = p0 + wave*32 + n;
  const ushort* inU = (const ushort*)in8;
  const ushort* wU  = (const ushort*)wA;

  f32x4 acc[4][2];
  #pragma unroll
  for(int i=0;i<4;i++)
    #pragma unroll
    for(int j=0;j<2;j++)
      #pragma unroll
      for(int r=0;r<4;r++) acc[i][j][r] = 0.f;

  #pragma unroll
  for(int k0=0;k0<NC;k0+=32){
    size_t gb = ((size_t)(b*32) + (k0>>3) + quad)*NHW;
    short8 b0 = *(const short8*)&inU[(gb + pix0)*8];
    short8 b1 = *(const short8*)&inU[(gb + pix0 + 16)*8];
    #pragma unroll
    for(int mt=0;mt<4;mt++){
      short8 a = *(const short8*)&wU[(size_t)(Moff + mt*16 + n)*NC + k0 + quad*8];
      acc[mt][0] = __builtin_amdgcn_mfma_f32_16x16x32_bf16(a, b0, acc[mt][0], 0, 0, 0);
      acc[mt][1] = __builtin_amdgcn_mfma_f32_16x16x32_bf16(a, b1, acc[mt][1], 0, 0, 0);
    }
  }

  if(MODE == 0){
    #pragma unroll
    for(int ng=0;ng<2;ng++){
      size_t pix = pix0 + ng*16;
      int py = ((int)(pix>>7) + 1)*HP + (int)(pix&127) + 1;
      #pragma unroll
      for(int mt=0;mt<4;mt++){
        int mg  = (Moff>>3) + mt*2 + (quad>>1);
        int off = (quad&1)*4;
        union { ushort u[4]; ushort4 v; } t;
        #pragma unroll
        for(int r=0;r<4;r++){
          int m = Moff + mt*16 + quad*4 + r;
          float v = acc[mt][ng][r]*(g[m]*BN_S) + bias[m];
          bf16 ab = f2b(fmaxf(v, 0.f));
          t.u[r] = *(ushort*)&ab;
        }
        *(ushort4*)((ushort*)h1p + (((size_t)(b*16+mg))*HPP + py)*8 + off) = t.v;
      }
    }
  }else{
    #pragma unroll
    for(int ng=0;ng<2;ng++){
      float ph = 0.f;
      #pragma unroll
      for(int mt=0;mt<4;mt++){
        #pragma unroll
        for(int r=0;r<4;r++){
          int m = mt*16 + quad*4 + r;
          float v = acc[mt][ng][r]*(g[m]*BN_S) + bias[m];
          ph += fmaxf(v, 0.f) * hw[m];
        }
      }
      ph += __shfl_xor(ph, 16);
      ph += __shfl_xor(ph, 32);
      if(lane < 16){
        int pix = p0 + wave*32 + ng*16 + lane;
        float sg = 1.f/(1.f + expf(-(ph + hb[0])));
        outMap[(size_t)b*NHW + pix] = 0.03f + sg*0.37f;
      }
    }
  }
}

// ============ 3x3 conv on padded h1, M split in 2; partial heat-head sums out ============
__global__ __launch_bounds__(256) void k_c3(const bf16* __restrict__ h1p,
                                            const bf16* __restrict__ wT,    // (tau,m,c)
                                            const float* __restrict__ g,
                                            const float* __restrict__ bias,
                                            const float* __restrict__ hw,
                                            float* __restrict__ partialH){  // (2,B,NHW)
  int tid = threadIdx.x;
  int y = blockIdx.x, b = blockIdx.y;
  int Moff = blockIdx.z*64;
  int lane = tid & 63, wave = tid >> 6;
  int n = lane & 15, quad = lane >> 4;
  const ushort* inU = (const ushort*)h1p;
  const ushort* wU  = (const ushort*)wT;
  f32x4 acc[4][2];
  #pragma unroll
  for(int i=0;i<4;i++)
    #pragma unroll
    for(int j=0;j<2;j++)
      #pragma unroll
      for(int r=0;r<4;r++) acc[i][j][r] = 0.f;

  int colbase = wave*32 + n;
  for(int dy=0;dy<3;dy++){
    #pragma unroll
    for(int dx=0;dx<3;dx++){
      const ushort* wtb = wU + (size_t)(dy*3+dx)*MID*MID + (size_t)Moff*MID;
      #pragma unroll
      for(int k0=0;k0<MID;k0+=32){
        size_t base = ((size_t)(b*16) + (k0>>3) + quad)*HPP + (size_t)(y+dy)*HP + colbase + dx;
        short8 b0 = *(const short8*)&inU[base*8];
        short8 b1 = *(const short8*)&inU[(base+16)*8];
        #pragma unroll
        for(int mt=0;mt<4;mt++){
          short8 a = *(const short8*)&wtb[(size_t)(mt*16 + n)*MID + k0 + quad*8];
          acc[mt][0] = __builtin_amdgcn_mfma_f32_16x16x32_bf16(a, b0, acc[mt][0], 0, 0, 0);
          acc[mt][1] = __builtin_amdgcn_mfma_f32_16x16x32_bf16(a, b1, acc[mt][1], 0, 0, 0);
        }
      }
    }
  }
  #pragma unroll
  for(int ng=0;ng<2;ng++){
    float ph = 0.f;
    #pragma unroll
    for(int mt=0;mt<4;mt++){
      #pragma unroll
      for(int r=0;r<4;r++){
        int m = Moff + mt*16 + quad*4 + r;
        float v = acc[mt][ng][r]*(g[m]*BN_S) + bias[m];
        ph += fmaxf(v, 0.f) * hw[m];
      }
    }
    ph += __shfl_xor(ph, 16);
    ph += __shfl_xor(ph, 32);
    if(lane < 16){
      int pix = y*NW + wave*32 + ng*16 + lane;
      partialH[((size_t)blockIdx.z*NB + b)*NHW + pix] = ph;
    }
  }
}

// ---------------- combine partial head sums -> heat sigmoid ----------------
__global__ __launch_bounds__(256) void k_heat(const float* __restrict__ partialH,
                                              const float* __restrict__ hb,
                                              float* __restrict__ heatF,
                                              float* __restrict__ out){
  int p = blockIdx.x*256 + threadIdx.x;
  int b = blockIdx.y;
  float logit = partialH[(size_t)b*NHW + p] + partialH[(size_t)(NB + b)*NHW + p] + hb[0];
  float sg = 1.f/(1.f + expf(-logit));
  heatF[(size_t)b*NHW + p] = sg;
  out[((size_t)(b*2+1))*NHW + p] = sg;
}

// ---------------- topk stage 1 ----------------
__global__ __launch_bounds__(256) void k_topk1(const float* __restrict__ heat,
                                               float* __restrict__ sv_g,
                                               int*   __restrict__ si_g){
  __shared__ float sv[256*5];
  __shared__ int   si[256*5];
  int blk = blockIdx.x, b = blockIdx.y, tid = threadIdx.x;
  const float* hb = heat + (size_t)b*NHW;
  float tv[5]; int ti[5];
  #pragma unroll
  for(int i=0;i<5;i++){ tv[i] = -1.f; ti[i] = 0x7fffffff; }
  for(int s=0;s<2;s++){
    int p = blk*512 + s*256 + tid;
    int y = p >> 7, x = p & 127;
    float v = hb[p];
    float mx = v;
    for(int dy=-1;dy<=1;dy++){
      int yy = y+dy; if(yy<0||yy>=NH) continue;
      for(int dx=-1;dx<=1;dx++){
        int xc = x+dx; if(xc<0||xc>=NW) continue;
        mx = fmaxf(mx, hb[yy*NW+xc]);
      }
    }
    float pv = (v == mx) ? v : 0.f;
    #pragma unroll
    for(int j=0;j<5;j++){
      if(pv > tv[j] || (pv == tv[j] && p < ti[j])){
        for(int q=4;q>j;q--){ tv[q]=tv[q-1]; ti[q]=ti[q-1]; }
        tv[j] = pv; ti[j] = p;
        break;
      }
    }
  }
  #pragma unroll
  for(int i=0;i<5;i++){ sv[tid*5+i] = tv[i]; si[tid*5+i] = ti[i]; }
  __syncthreads();
  if(tid < 64){
    float mv[5]; int mi[5];
    #pragma unroll
    for(int i=0;i<5;i++){ mv[i] = -1.f; mi[i] = 0x7fffffff; }
    for(int s=0;s<4;s++){
      int t2 = tid + s*64;
      for(int i=0;i<5;i++){
        float pv = sv[t2*5+i]; int pi = si[t2*5+i];
        for(int j=0;j<5;j++){
          if(pv > mv[j] || (pv == mv[j] && pi < mi[j])){
            for(int q=4;q>j;q--){ mv[q]=mv[q-1]; mi[q]=mi[q-1]; }
            mv[j] = pv; mi[j] = pi;
            break;
          }
        }
      }
    }
    for(int i=0;i<5;i++){ sv[tid*5+i] = mv[i]; si[tid*5+i] = mi[i]; }
  }
  __syncthreads();
  if(tid == 0){
    float fv[5]; int fi[5];
    #pragma unroll
    for(int i=0;i<5;i++){ fv[i] = -1.f; fi[i] = 0x7fffffff; }
    for(int t2=0;t2<64;t2++){
      for(int i=0;i<5;i++){
        float pv = sv[t2*5+i]; int pi = si[t2*5+i];
        for(int j=0;j<5;j++){
          if(pv > fv[j] || (pv == fv[j] && pi < fi[j])){
            for(int q=4;q>j;q--){ fv[q]=fv[q-1]; fi[q]=fi[q-1]; }
            fv[j] = pv; fi[j] = pi;
            break;
          }
        }
      }
    }
    for(int i=0;i<5;i++){
      sv_g[(b*32 + blk)*5 + i] = fv[i];
      si_g[(b*32 + blk)*5 + i] = fi[i];
    }
  }
}

// ---------------- topk stage 2 ----------------
__global__ __launch_bounds__(256) void k_topk2(const float* __restrict__ sv_g,
                                               const int*   __restrict__ si_g,
                                               float* __restrict__ centers){
  __shared__ float cv[160];
  __shared__ int   ci[160];
  int b = blockIdx.x, tid = threadIdx.x;
  if(tid < 160){ cv[tid] = sv_g[b*160 + tid]; ci[tid] = si_g[b*160 + tid]; }
  __syncthreads();
  if(tid < 160){
    float v = cv[tid]; int idx = ci[tid];
    int rank = 0;
    for(int j=0;j<160;j++){
      float vj = cv[j]; int ij = ci[j];
      rank += (vj > v || (vj == v && ij < idx)) ? 1 : 0;
    }
    if(rank < 5){
      float valid = (v >= 0.1f) ? 1.f : 0.f;
      float row = (float)(idx >> 7);
      float col = (float)(idx & 127);
      float ny = 2.f*row/127.f - 1.f;
      float nx = 2.f*col/127.f - 1.f;
      float* cp = centers + (b*5+rank)*4;
      cp[0] = nx*valid; cp[1] = ny*valid; cp[2] = v; cp[3] = valid;
    }
  }
}

// ---------------- per-(b,k): bilinear sample + MLP -> gaussian params ----------------
__global__ __launch_bounds__(256) void k_params(const float* __restrict__ x,
                                                const float* __restrict__ rmap,
                                                const float* __restrict__ centers,
                                                const float* __restrict__ w1,
                                                const float* __restrict__ b1,
                                                const float* __restrict__ w2,
                                                const float* __restrict__ b2,
                                                const float* __restrict__ log_alpha,
                                                float* __restrict__ params){
  __shared__ float feat[NC];
  __shared__ float hmid[128];
  __shared__ float pp[4];
  int bk = blockIdx.x;
  int b = bk/5;
  int tid = threadIdx.x;
  float cx = centers[bk*4+0];
  float cy = centers[bk*4+1];
  float valid = centers[bk*4+3];
  float px = fminf(fmaxf((cx+1.f)*0.5f*(NW-1), 0.f), (float)(NW-1));
  float py = fminf(fmaxf((cy+1.f)*0.5f*(NH-1), 0.f), (float)(NH-1));
  int x0 = (int)floorf(px); int x1 = min(x0+1, NW-1);
  int y0 = (int)floorf(py); int y1 = min(y0+1, NH-1);
  float wx = px - (float)x0, wy = py - (float)y0;
  {
    const float* xb = x + ((size_t)b*NC + tid)*NHW;
    float v00 = xb[y0*NW+x0], v01 = xb[y0*NW+x1];
    float v10 = xb[y1*NW+x0], v11 = xb[y1*NW+x1];
    feat[tid] = (1.f-wy)*((1.f-wx)*v00 + wx*v01) + wy*((1.f-wx)*v10 + wx*v11);
  }
  __syncthreads();
  if(tid < 128){
    float a = b1[tid];
    for(int c=0;c<NC;c++) a += feat[c]*w1[c*128+tid];
    hmid[tid] = fmaxf(a, 0.f);
  }
  __syncthreads();
  if(tid < 4){
    float a = b2[tid];
    for(int j=0;j<128;j++) a += hmid[j]*w2[j*4+tid];
    pp[tid] = a;
  }
  __syncthreads();
  if(tid == 0){
    const float* rb = rmap + (size_t)b*NHW;
    float r00 = rb[y0*NW+x0], r01 = rb[y0*NW+x1];
    float r10 = rb[y1*NW+x0], r11 = rb[y1*NW+x1];
    float rk = (1.f-wy)*((1.f-wx)*r00 + wx*r01) + wy*((1.f-wx)*r10 + wx*r11);
    float la = log_alpha[0];
    float alpha = logf(1.f + expf(la));
    float dsx = tanhf(pp[0])*0.08f;
    float dsy = tanhf(pp[1])*0.08f;
    float theta = tanhf(pp[2])*3.14159265358979323846f;
    float wgt = 1.f/(1.f + expf(-pp[3]));
    float sx = fminf(fmaxf(alpha*rk + dsx, 0.05f), 0.45f);
    float sy = fminf(fmaxf(alpha*rk*1.5f + dsy, 0.05f), 0.45f);
    float* P = params + bk*8;
    P[0] = cx; P[1] = cy;
    P[2] = cosf(theta); P[3] = sinf(theta);
    P[4] = 1.f/(2.f*sx*sx + 1e-6f);
    P[5] = 1.f/(2.f*sy*sy + 1e-6f);
    P[6] = wgt*valid; P[7] = valid;
  }
}

// ---------------- gaussian mixture -> attn (out ch0) ----------------
__global__ __launch_bounds__(256) void k_attn(const float* __restrict__ params,
                                              float* __restrict__ out){
  int tid = threadIdx.x;
  int p = blockIdx.x*256 + tid;
  int b = blockIdx.y;
  int y = p >> 7, x = p & 127;
  float gx = -1.f + 2.f*(float)x/127.f;
  float gy = -1.f + 2.f*(float)y/127.f;
  const float* Pb = params + b*40;
  float wsum = 0.f;
  #pragma unroll
  for(int k=0;k<5;k++) wsum += Pb[k*8+6];
  wsum = fmaxf(wsum, 1e-6f);
  float mix = 0.f;
  #pragma unroll
  for(int k=0;k<5;k++){
    const float* P = Pb + k*8;
    float dx = gx - P[0], dy = gy - P[1];
    float xr =  P[2]*dx + P[3]*dy;
    float yr = -P[3]*dx + P[2]*dy;
    float e = __expf(-(xr*xr*P[4] + yr*yr*P[5]));
    mix += e * (P[6]/wsum);
  }
  float attn = 1.f/(1.f + __expf(-(4.f*mix - 2.f)));
  out[((size_t)(b*2))*NHW + p] = attn;
}

extern "C" void kernel_launch(void* const* d_in, const int* in_sizes, int n_in,
                              void* d_out, int out_size, void* d_ws, size_t ws_size,
                              hipStream_t stream){
  const float* x        = (const float*)d_in[0];
  const float* hm_dw    = (const float*)d_in[1];
  const float* hm_pw1   = (const float*)d_in[2];
  const float* hm_g1    = (const float*)d_in[3];
  const float* hm_b1    = (const float*)d_in[4];
  const float* hm_c3    = (const float*)d_in[5];
  const float* hm_g2    = (const float*)d_in[6];
  const float* hm_b2    = (const float*)d_in[7];
  const float* hm_out_w = (const float*)d_in[8];
  const float* hm_out_b = (const float*)d_in[9];
  const float* r_dw     = (const float*)d_in[10];
  const float* r_pw1    = (const float*)d_in[11];
  const float* r_g      = (const float*)d_in[12];
  const float* r_b      = (const float*)d_in[13];
  const float* r_out_w  = (const float*)d_in[14];
  const float* r_out_b  = (const float*)d_in[15];
  const float* log_alpha= (const float*)d_in[16];
  const float* mlp_w1   = (const float*)d_in[17];
  const float* mlp_b1   = (const float*)d_in[18];
  const float* mlp_w2   = (const float*)d_in[19];
  const float* mlp_b2   = (const float*)d_in[20];
  float* out = (float*)d_out;

  const size_t SZ_DW  = 67108864;   // (B,32,NHW,8) bf16
  const size_t SZ_H1P = 34611200;   // (B,16,HPP,8) bf16
  char* ws = (char*)d_ws;

  // big layout: two dw buffers (dual-dw kernel); small layout: one reused buffer
  bool big = ws_size >= (2*SZ_DW + SZ_H1P + 2*1024*1024);
  bf16* dwXh = (bf16*)ws;
  bf16* dwXr = big ? (bf16*)(ws + SZ_DW) : dwXh;
  size_t off = (big ? 2*SZ_DW : SZ_DW);
  bf16*  h1p   = (bf16*)(ws + off);               off += SZ_H1P;
  float* heatF = (float*)(ws + off);              off += 524288;
  float* rmapF = (float*)(ws + off);              off += 524288;
  bf16*  wT    = (bf16*)(ws + off);               off += 294912;
  bf16*  wPW1h = (bf16*)(ws + off);               off += 65536;
  bf16*  wPW1r = (bf16*)(ws + off);               off += 32768;
  float* tsv   = (float*)(ws + off);              off += 5120;
  int*   tsi   = (int*)(ws + off);                off += 5120;
  float* centers = (float*)(ws + off);            off += 640;
  float* params  = (float*)(ws + off);            off += 1280;
  float* partialH = (float*)ws;   // (2,B,NHW) f32 = 1 MB, aliases dwXh (dead by k_c3)

  // prep (tiny)
  k_cvt  <<<dim3(128), dim3(256), 0, stream>>>(hm_pw1, wPW1h, 128*256);
  k_cvt  <<<dim3(64),  dim3(256), 0, stream>>>(r_pw1,  wPW1r, 64*256);
  k_trans<<<dim3(576), dim3(256), 0, stream>>>(hm_c3, wT);
  k_zero <<<dim3((NB*16*516 + 255)/256), dim3(256), 0, stream>>>(h1p);

  if(big){
    k_dwb2<<<dim3(16, 32, NB), dim3(256), 0, stream>>>(x, hm_dw, r_dw, dwXh, dwXr);
    k_pw<1><<<dim3(1024, 1), dim3(256), 0, stream>>>(dwXr, wPW1r, r_g, r_b, r_out_w, r_out_b,
                                                     (bf16*)nullptr, rmapF);
    k_pw<0><<<dim3(1024, 2), dim3(256), 0, stream>>>(dwXh, wPW1h, hm_g1, hm_b1,
                                                     (const float*)nullptr, (const float*)nullptr,
                                                     h1p, (float*)nullptr);
  }else{
    k_dwb<<<dim3(16, 32, NB), dim3(256), 0, stream>>>(x, r_dw, dwXr);
    k_pw<1><<<dim3(1024, 1), dim3(256), 0, stream>>>(dwXr, wPW1r, r_g, r_b, r_out_w, r_out_b,
                                                     (bf16*)nullptr, rmapF);
    k_dwb<<<dim3(16, 32, NB), dim3(256), 0, stream>>>(x, hm_dw, dwXh);
    k_pw<0><<<dim3(1024, 2), dim3(256), 0, stream>>>(dwXh, wPW1h, hm_g1, hm_b1,
                                                     (const float*)nullptr, (const float*)nullptr,
                                                     h1p, (float*)nullptr);
  }
  // c3 (M split in 2) -> partial head sums; combine -> heatF/out ch1
  k_c3<<<dim3(128, NB, 2), dim3(256), 0, stream>>>(h1p, wT, hm_g2, hm_b2, hm_out_w, partialH);
  k_heat<<<dim3(64, NB), dim3(256), 0, stream>>>(partialH, hm_out_b, heatF, out);
  // topk -> centers; params; attn
  k_topk1<<<dim3(32, NB), dim3(256), 0, stream>>>(heatF, tsv, tsi);
  k_topk2<<<dim3(NB), dim3(256), 0, stream>>>(tsv, tsi, centers);
  k_params<<<dim3(NB*5), dim3(256), 0, stream>>>(x, rmapF, centers, mlp_w1, mlp_b1, mlp_w2, mlp_b2, log_alpha, params);
  k_attn<<<dim3(64, NB), dim3(256), 0, stream>>>(params, out);
}